// Round 24
// baseline (270.912 us; speedup 1.0000x reference)
//
#include <hip/hip_runtime.h>
#include <hip/hip_fp16.h>

#define N_NODES 100000
#define N_EDGES 3200000
#define BUCKET_NODES 128
#define NB 782            // fine buckets (128 dst nodes each)
#define CHS 8192          // scatter chunk (runs ~10.5 edges, 1.5x amp)
#define NSC 391           // ceil(N_EDGES / CHS)
#define FS_CAP 4608       // finesort LDS capacity (mean bucket 4096, +8 sigma)
#define NPROJ 782         // node_proj blocks (grid-stride over 1563 groups of 64)
#define NG64 1563         // ceil(100000/64)
#define NHIST 512         // fhist blocks

typedef __attribute__((ext_vector_type(8))) short bf16x8;
typedef __attribute__((ext_vector_type(4))) float f32x4;

__device__ __forceinline__ unsigned short f2bf(float f) {
    unsigned u = __float_as_uint(f);
    unsigned r = (u + 0x7FFFu + ((u >> 16) & 1u)) >> 16;   // RNE
    return (unsigned short)r;
}
__device__ __forceinline__ float bf2f(unsigned short h) {
    return __uint_as_float(((unsigned)h) << 16);
}

// ---------------------------------------------------------------------------
// node_proj (MFMA, R22-proven): feat = node_feat @ Wfc.T via
// mfma_f32_16x16x32_bf16. B staged fragment-linear in LDS (16 KB).
// ---------------------------------------------------------------------------
__global__ __launch_bounds__(256) void node_proj(
    const float* __restrict__ node_feat,
    const float* __restrict__ Wfc,
    const float* __restrict__ attn_l,
    const float* __restrict__ attn_r,
    unsigned short* __restrict__ featb,
    float* __restrict__ el,
    float* __restrict__ er)
{
    __shared__ short Wb[8192];          // 16 KB bf16, fragment-linear
    const int tid = threadIdx.x;
    for (int i = tid; i < 8192; i += 256) {
        const int e   = i & 7;
        const int col = (i >> 3) & 15;
        const int q   = (i >> 7) & 3;
        const int kk  = (i >> 9) & 3;
        const int t   = (i >> 11) & 3;
        Wb[i] = (short)f2bf(Wfc[(t * 16 + col) * 128 + kk * 32 + q * 8 + e]);
    }
    __syncthreads();

    const int lane = tid & 63;
    const int w = tid >> 6;
    const int col = lane & 15;
    const int q = lane >> 4;

    float alv[4], arv[4];
    #pragma unroll
    for (int t = 0; t < 4; ++t) {
        alv[t] = attn_l[t * 16 + col];
        arv[t] = attn_r[t * 16 + col];
    }

    for (int g = blockIdx.x; g < NG64; g += NPROJ) {
        const int n0 = g * 64 + w * 16;
        if (n0 >= N_NODES) continue;     // 100000 % 16 == 0 -> no partial wave

        f32x4 acc0 = {0.f,0.f,0.f,0.f}, acc1 = {0.f,0.f,0.f,0.f};
        f32x4 acc2 = {0.f,0.f,0.f,0.f}, acc3 = {0.f,0.f,0.f,0.f};

        #pragma unroll
        for (int kk = 0; kk < 4; ++kk) {
            const float* ap = node_feat + (size_t)(n0 + col) * 128 + kk * 32 + q * 8;
            const float4 a0 = *(const float4*)ap;
            const float4 a1 = *(const float4*)(ap + 4);
            bf16x8 af;
            af[0] = (short)f2bf(a0.x); af[1] = (short)f2bf(a0.y);
            af[2] = (short)f2bf(a0.z); af[3] = (short)f2bf(a0.w);
            af[4] = (short)f2bf(a1.x); af[5] = (short)f2bf(a1.y);
            af[6] = (short)f2bf(a1.z); af[7] = (short)f2bf(a1.w);

            const bf16x8 b0 = *(const bf16x8*)&Wb[(((0*4+kk)*4+q)*16 + col)*8];
            const bf16x8 b1 = *(const bf16x8*)&Wb[(((1*4+kk)*4+q)*16 + col)*8];
            const bf16x8 b2 = *(const bf16x8*)&Wb[(((2*4+kk)*4+q)*16 + col)*8];
            const bf16x8 b3 = *(const bf16x8*)&Wb[(((3*4+kk)*4+q)*16 + col)*8];
            acc0 = __builtin_amdgcn_mfma_f32_16x16x32_bf16(af, b0, acc0, 0, 0, 0);
            acc1 = __builtin_amdgcn_mfma_f32_16x16x32_bf16(af, b1, acc1, 0, 0, 0);
            acc2 = __builtin_amdgcn_mfma_f32_16x16x32_bf16(af, b2, acc2, 0, 0, 0);
            acc3 = __builtin_amdgcn_mfma_f32_16x16x32_bf16(af, b3, acc3, 0, 0, 0);
        }

        #pragma unroll
        for (int m = 0; m < 4; ++m) {
            const size_t rb = (size_t)(n0 + q * 4 + m) * 64;
            featb[rb + 0 * 16 + col] = f2bf(acc0[m]);
            featb[rb + 1 * 16 + col] = f2bf(acc1[m]);
            featb[rb + 2 * 16 + col] = f2bf(acc2[m]);
            featb[rb + 3 * 16 + col] = f2bf(acc3[m]);
        }

        #pragma unroll
        for (int m = 0; m < 4; ++m) {
            float pl0 = acc0[m] * alv[0], pr0 = acc0[m] * arv[0];
            float pl1 = acc1[m] * alv[1], pr1 = acc1[m] * arv[1];
            float pl2 = acc2[m] * alv[2], pr2 = acc2[m] * arv[2];
            float pl3 = acc3[m] * alv[3], pr3 = acc3[m] * arv[3];
            #pragma unroll
            for (int off = 8; off >= 1; off >>= 1) {
                pl0 += __shfl_xor(pl0, off); pr0 += __shfl_xor(pr0, off);
                pl1 += __shfl_xor(pl1, off); pr1 += __shfl_xor(pr1, off);
                pl2 += __shfl_xor(pl2, off); pr2 += __shfl_xor(pr2, off);
                pl3 += __shfl_xor(pl3, off); pr3 += __shfl_xor(pr3, off);
            }
            if (col == 0) {
                const size_t eb = (size_t)(n0 + q * 4 + m) * 4;
                el[eb + 0] = pl0; el[eb + 1] = pl1; el[eb + 2] = pl2; el[eb + 3] = pl3;
                er[eb + 0] = pr0; er[eb + 1] = pr1; er[eb + 2] = pr2; er[eb + 3] = pr3;
            }
        }
    }
}

// ---------------------------------------------------------------------------
// fhist: fine histogram (782), one LDS atomic per edge, int4 loads.
// ---------------------------------------------------------------------------
__global__ __launch_bounds__(256) void fhist(
    const int* __restrict__ dst,
    int* __restrict__ ftot)           // NB fine totals
{
    __shared__ int h[NB];
    const int tid = threadIdx.x;
    for (int i = tid; i < NB; i += 256) h[i] = 0;
    __syncthreads();
    const int stride = NHIST * 256;
    const int n4 = N_EDGES / 4;           // 800000
    for (int idx = blockIdx.x * 256 + tid; idx < n4; idx += stride) {
        const int4 d4 = ((const int4*)dst)[idx];
        atomicAdd(&h[d4.x >> 7], 1);
        atomicAdd(&h[d4.y >> 7], 1);
        atomicAdd(&h[d4.z >> 7], 1);
        atomicAdd(&h[d4.w >> 7], 1);
    }
    __syncthreads();
    for (int i = tid; i < NB; i += 256)
        if (h[i]) atomicAdd(&ftot[i], h[i]);
}

// ---------------------------------------------------------------------------
// Scan of 782 fine totals -> base + cursor. Single wave.
// ---------------------------------------------------------------------------
__global__ __launch_bounds__(64) void bscan(const int* __restrict__ ftot,
                                            int* __restrict__ base,
                                            int* __restrict__ fcursor)
{
    const int lane = threadIdx.x;
    int carry = 0;
    for (int ch = 0; ch < NB; ch += 64) {
        const int idx = ch + lane;
        const int v = (idx < NB) ? ftot[idx] : 0;
        int x = v;
        #pragma unroll
        for (int off = 1; off < 64; off <<= 1) {
            int y = __shfl_up(x, off);
            if (lane >= off) x += y;
        }
        const int excl = x - v + carry;
        if (idx < NB) { base[idx] = excl; fcursor[idx] = excl; }
        carry += __shfl(x, 63);
    }
    if (lane == 0) base[NB] = carry;
}

// ---------------------------------------------------------------------------
// Scatter (single-pass, direct to fine buckets): sigma-path while edge_feat
// streams coalesced; 12 B payload {src | dl<<17, ee01 fp16x2, ee23 fp16x2}
// into 782 fine buckets. CHS=8192, 1024 threads (16 waves), 391 blocks ->
// 2 blocks/CU. Replaces the two-pass radix (wA write+read+wB write deleted).
// ---------------------------------------------------------------------------
__global__ __launch_bounds__(1024) void scatter(
    const int* __restrict__ src,
    const int* __restrict__ dst,
    const float* __restrict__ edge_feat,
    const float* __restrict__ We,
    const float* __restrict__ el,
    const float* __restrict__ er,
    int* __restrict__ fcursor,
    uint3* __restrict__ wB)
{
    __shared__ int ldst[CHS];         // 32768 B
    __shared__ int lbase[NB];         //  3128 B
    __shared__ int lcnt[NB];          //  3128 B
    const int tid = threadIdx.x;
    for (int i = tid; i < NB; i += 1024) lcnt[i] = 0;
    __syncthreads();
    const int e0 = blockIdx.x * CHS;
    const int n = min(CHS, N_EDGES - e0);
    for (int i = tid; i < n; i += 1024) {
        const int d = dst[e0 + i];
        ldst[i] = d;
        atomicAdd(&lcnt[d >> 7], 1);
    }
    __syncthreads();
    for (int b = tid; b < NB; b += 1024) {
        const int c = lcnt[b];
        lbase[b] = c ? atomicAdd(&fcursor[b], c) : 0;
        lcnt[b] = 0;
    }
    __syncthreads();

    const float4 W0 = ((const float4*)We)[0];
    const float4 W1 = ((const float4*)We)[1];
    const float4 W2 = ((const float4*)We)[2];
    const float4 W3 = ((const float4*)We)[3];

    for (int i = tid; i < n; i += 1024) {
        const int e = e0 + i;
        const int d = ldst[i];
        const int fb = d >> 7;
        const int r = atomicAdd(&lcnt[fb], 1);
        const int pos = lbase[fb] + r;

        const int s = src[e];
        const float4 ef = ((const float4*)edge_feat)[e];
        const float4 l4 = ((const float4*)el)[s];
        const float4 r4 = ((const float4*)er)[d];

        float t0 = l4.x + r4.x; t0 = t0 > 0.f ? t0 : 0.2f * t0;
        float t1 = l4.y + r4.y; t1 = t1 > 0.f ? t1 : 0.2f * t1;
        float t2 = l4.z + r4.z; t2 = t2 > 0.f ? t2 : 0.2f * t2;
        float t3 = l4.w + r4.w; t3 = t3 > 0.f ? t3 : 0.2f * t3;

        const float ee0 = __expf(t0 * (W0.x * ef.x + W0.y * ef.y + W0.z * ef.z + W0.w * ef.w));
        const float ee1 = __expf(t1 * (W1.x * ef.x + W1.y * ef.y + W1.z * ef.z + W1.w * ef.w));
        const float ee2 = __expf(t2 * (W2.x * ef.x + W2.y * ef.y + W2.z * ef.z + W2.w * ef.w));
        const float ee3 = __expf(t3 * (W3.x * ef.x + W3.y * ef.y + W3.z * ef.z + W3.w * ef.w));

        const unsigned h0 = __half_as_ushort(__float2half_rn(ee0));
        const unsigned h1 = __half_as_ushort(__float2half_rn(ee1));
        const unsigned h2 = __half_as_ushort(__float2half_rn(ee2));
        const unsigned h3 = __half_as_ushort(__float2half_rn(ee3));

        wB[pos] = make_uint3((unsigned)s | ((unsigned)(d & (BUCKET_NODES - 1)) << 17),
                             h0 | (h1 << 16), h2 | (h3 << 16));
    }
}

// ---------------------------------------------------------------------------
// Finesort: one block (1024 threads) per fine bucket. Counting-sort by
// dst-local IN PLACE, emit per-node CSR offsets. Output payload x is the
// PRE-SCALED featb byte offset (si*128).
// ---------------------------------------------------------------------------
__global__ __launch_bounds__(1024) void finesort(
    const int* __restrict__ base,
    uint3* __restrict__ wP,
    int* __restrict__ node_off)
{
    __shared__ uint3 sP[FS_CAP];          // 54 KB
    __shared__ int hist[BUCKET_NODES];
    __shared__ int cur[BUCKET_NODES];
    const int b = blockIdx.x;
    const int s = base[b];
    int cnt = base[b + 1] - s;
    if (cnt > FS_CAP) cnt = FS_CAP;   // unreachable; safety
    const int tid = threadIdx.x;
    if (tid < BUCKET_NODES) hist[tid] = 0;
    __syncthreads();
    for (int i = tid; i < cnt; i += 1024) {
        const uint3 p = wP[s + i];
        sP[i] = p;
        atomicAdd(&hist[(p.x >> 17) & (BUCKET_NODES - 1)], 1);
    }
    __syncthreads();
    if (tid < 64) {
        int carry = 0;
        for (int ch = 0; ch < BUCKET_NODES; ch += 64) {
            const int v = hist[ch + tid];
            int x = v;
            #pragma unroll
            for (int off = 1; off < 64; off <<= 1) {
                int y = __shfl_up(x, off);
                if (tid >= off) x += y;
            }
            const int excl = x - v + carry;
            cur[ch + tid] = excl;
            const int node = b * BUCKET_NODES + ch + tid;
            if (node < N_NODES) node_off[node] = s + excl;
            carry += __shfl(x, 63);
        }
        if (tid == 0 && b == NB - 1) node_off[N_NODES] = N_EDGES;
    }
    __syncthreads();
    for (int i = tid; i < cnt; i += 1024) {
        const uint3 p = sP[i];
        const int dl = (p.x >> 17) & (BUCKET_NODES - 1);
        const int r = atomicAdd(&cur[dl], 1);
        // emit pre-scaled byte offset: si*128 (si = x & 0x1FFFF -> fits 2^24)
        wP[s + r] = make_uint3((p.x & 0x1FFFFu) << 7, p.y, p.z);
    }
}

// ---------------------------------------------------------------------------
// Aggregate v5 (R17-proven): one wave per dst node, split-wave 2 edges/iter.
// ---------------------------------------------------------------------------
__global__ __launch_bounds__(256) void aggregate(
    const int* __restrict__ node_off,
    const uint3* __restrict__ wP,
    const unsigned short* __restrict__ featb,
    float* __restrict__ rst)
{
    __shared__ float lee[4][64][4];   // [wave][edge][c]   16 KB
    __shared__ unsigned lsi[4][64];   // pre-scaled byte offsets  1 KB
    const int tid = threadIdx.x;
    const int node = (int)((blockIdx.x * 256 + tid) >> 6);
    const int lane = tid & 63;
    const int w = tid >> 6;
    if (node >= N_NODES) return;
    const int half = lane >> 5;                   // which edge of the pair
    const int j = lane & 31;                      // feature-pair index
    const int cc = j >> 3;                        // channel of features 2j,2j+1
    const unsigned jByte = (unsigned)j * 4u;      // byte offset of pair in row
    const unsigned char* __restrict__ fbyte = (const unsigned char*)featb;

    const int start = node_off[node];
    const int end = node_off[node + 1];

    float acc0 = 0.f, acc1 = 0.f;
    float s0 = 0.f, s1 = 0.f, s2 = 0.f, s3 = 0.f;

    for (int bat = start; bat < end; bat += 64) {
        const int n = min(64, end - bat);
        if (lane < n) {
            const uint3 p = wP[bat + lane];
            const float e0 = __half2float(__ushort_as_half((unsigned short)(p.y & 0xffffu)));
            const float e1 = __half2float(__ushort_as_half((unsigned short)(p.y >> 16)));
            const float e2 = __half2float(__ushort_as_half((unsigned short)(p.z & 0xffffu)));
            const float e3 = __half2float(__ushort_as_half((unsigned short)(p.z >> 16)));
            lsi[w][lane] = p.x;                    // si*128 (pre-scaled)
            *(float4*)&lee[w][lane][0] = make_float4(e0, e1, e2, e3);
            s0 += e0; s1 += e1; s2 += e2; s3 += e3;
        } else {
            lsi[w][lane] = 0;
            *(float4*)&lee[w][lane][0] = make_float4(0.f, 0.f, 0.f, 0.f);
        }
        __builtin_amdgcn_wave_barrier();   // keep LDS write->read in program order
        const int iters = (n + 1) >> 1;
        for (int i = 0; i < iters; ++i) {
            const int e = 2 * i + half;            // my half's edge (zeroed if >= n)
            const unsigned so = lsi[w][e];
            const float eec = lee[w][e][cc];
            const unsigned fr = *(const unsigned*)(fbyte + so + jByte);
            acc0 = fmaf(eec, bf2f((unsigned short)(fr & 0xffffu)), acc0);
            acc1 = fmaf(eec, bf2f((unsigned short)(fr >> 16)), acc1);
        }
        __builtin_amdgcn_wave_barrier();   // WAR: next batch overwrites lee
    }

    // merge halves (even-edge + odd-edge partial sums)
    acc0 += __shfl_xor(acc0, 32);
    acc1 += __shfl_xor(acc1, 32);

    #pragma unroll
    for (int off = 32; off >= 1; off >>= 1) {
        s0 += __shfl_xor(s0, off);
        s1 += __shfl_xor(s1, off);
        s2 += __shfl_xor(s2, off);
        s3 += __shfl_xor(s3, off);
    }

    // redistribute: lane l takes feature l = 2*(l>>1) + (l&1) from lane l>>1
    const float v0 = __shfl(acc0, lane >> 1);
    const float v1 = __shfl(acc1, lane >> 1);
    const float accL = (lane & 1) ? v1 : v0;
    const int c = lane >> 4;
    const float ssum = (c == 0) ? s0 : ((c == 1) ? s1 : ((c == 2) ? s2 : s3));
    rst[(size_t)node * 64 + lane] = (end > start) ? accL / ssum : 0.f;
}

// ---------------------------------------------------------------------------
extern "C" void kernel_launch(void* const* d_in, const int* in_sizes, int n_in,
                              void* d_out, int out_size, void* d_ws, size_t ws_size,
                              hipStream_t stream)
{
    const float* node_feat = (const float*)d_in[0];
    const float* edge_feat = (const float*)d_in[1];
    const int*   src       = (const int*)d_in[2];
    const int*   dst       = (const int*)d_in[3];
    const float* Wfc       = (const float*)d_in[4];
    const float* We        = (const float*)d_in[5];
    const float* attn_l    = (const float*)d_in[6];
    const float* attn_r    = (const float*)d_in[7];
    float* rst = (float*)d_out;

    char* ws = (char*)d_ws;
    unsigned short* featb = (unsigned short*)(ws);        // 12,800,000 B
    float* el       = (float*)(ws + 12800000);            //  1,600,000 B
    float* er       = (float*)(ws + 14400000);            //  1,600,000 B
    int*   ftot     = (int*)  (ws + 16000000);            //      3,128 B
    int*   base     = (int*)  (ws + 16003200);            //      3,132 B
    int*   fcursor  = (int*)  (ws + 16006400);            //      3,128 B
    int*   node_off = (int*)  (ws + 16009600);            //    400,004 B
    uint3* wB       = (uint3*)(ws + 16409728);            // 38,400,000 B
                                                          // total ~54.8 MB

    hipMemsetAsync(ftot, 0, NB * sizeof(int), stream);

    node_proj<<<NPROJ, 256, 0, stream>>>(node_feat, Wfc, attn_l, attn_r, featb, el, er);
    fhist<<<NHIST, 256, 0, stream>>>(dst, ftot);
    bscan<<<1, 64, 0, stream>>>(ftot, base, fcursor);
    scatter<<<NSC, 1024, 0, stream>>>(src, dst, edge_feat, We, el, er, fcursor, wB);
    finesort<<<NB, 1024, 0, stream>>>(base, wB, node_off);
    aggregate<<<(N_NODES * 64 + 255) / 256, 256, 0, stream>>>(node_off, wB, featb, rst);
}

// Round 25
// 240.884 us; speedup vs baseline: 1.1247x; 1.1247x over previous
//
#include <hip/hip_runtime.h>
#include <hip/hip_fp16.h>

#define N_NODES 100000
#define N_EDGES 3200000
#define E0 1601536        // half boundary = 391*4096 (CHA-aligned, div by 4)
#define E1REM 1598464     // N_EDGES - E0
#define BUCKET_NODES 128
#define NB 782            // fine buckets (128 dst nodes each)
#define NBC 25            // coarse buckets (4096 nodes each) = ceil(100000/4096)
#define CNODES 4096       // nodes per coarse bucket
#define CHA 4096          // pass-A chunk: runs ~164 edges (~2 KB)
#define NPA0 391          // E0 / CHA exactly
#define NPA1 391          // ceil(E1REM / CHA), last block n=1024
#define CHB 4096          // pass-B chunk
#define NPB0 391
#define NPB1 391
#define FS_CAP 4608       // finesort LDS capacity (mean bucket 4096, +8 sigma)
#define NPROJ 782         // node_proj blocks (grid-stride over 1563 groups of 64)
#define NG64 1563         // ceil(100000/64)
#define NHIST 512         // fhist blocks

typedef __attribute__((ext_vector_type(8))) short bf16x8;
typedef __attribute__((ext_vector_type(4))) float f32x4;

__device__ __forceinline__ unsigned short f2bf(float f) {
    unsigned u = __float_as_uint(f);
    unsigned r = (u + 0x7FFFu + ((u >> 16) & 1u)) >> 16;   // RNE
    return (unsigned short)r;
}
__device__ __forceinline__ float bf2f(unsigned short h) {
    return __uint_as_float(((unsigned)h) << 16);
}

// ---------------------------------------------------------------------------
// node_proj (MFMA, R22-proven): feat = node_feat @ Wfc.T via
// mfma_f32_16x16x32_bf16. B staged fragment-linear in LDS (16 KB).
// ---------------------------------------------------------------------------
__global__ __launch_bounds__(256) void node_proj(
    const float* __restrict__ node_feat,
    const float* __restrict__ Wfc,
    const float* __restrict__ attn_l,
    const float* __restrict__ attn_r,
    unsigned short* __restrict__ featb,
    float* __restrict__ el,
    float* __restrict__ er)
{
    __shared__ short Wb[8192];          // 16 KB bf16, fragment-linear
    const int tid = threadIdx.x;
    for (int i = tid; i < 8192; i += 256) {
        const int e   = i & 7;
        const int col = (i >> 3) & 15;
        const int q   = (i >> 7) & 3;
        const int kk  = (i >> 9) & 3;
        const int t   = (i >> 11) & 3;
        Wb[i] = (short)f2bf(Wfc[(t * 16 + col) * 128 + kk * 32 + q * 8 + e]);
    }
    __syncthreads();

    const int lane = tid & 63;
    const int w = tid >> 6;
    const int col = lane & 15;
    const int q = lane >> 4;

    float alv[4], arv[4];
    #pragma unroll
    for (int t = 0; t < 4; ++t) {
        alv[t] = attn_l[t * 16 + col];
        arv[t] = attn_r[t * 16 + col];
    }

    for (int g = blockIdx.x; g < NG64; g += NPROJ) {
        const int n0 = g * 64 + w * 16;
        if (n0 >= N_NODES) continue;     // 100000 % 16 == 0 -> no partial wave

        f32x4 acc0 = {0.f,0.f,0.f,0.f}, acc1 = {0.f,0.f,0.f,0.f};
        f32x4 acc2 = {0.f,0.f,0.f,0.f}, acc3 = {0.f,0.f,0.f,0.f};

        #pragma unroll
        for (int kk = 0; kk < 4; ++kk) {
            const float* ap = node_feat + (size_t)(n0 + col) * 128 + kk * 32 + q * 8;
            const float4 a0 = *(const float4*)ap;
            const float4 a1 = *(const float4*)(ap + 4);
            bf16x8 af;
            af[0] = (short)f2bf(a0.x); af[1] = (short)f2bf(a0.y);
            af[2] = (short)f2bf(a0.z); af[3] = (short)f2bf(a0.w);
            af[4] = (short)f2bf(a1.x); af[5] = (short)f2bf(a1.y);
            af[6] = (short)f2bf(a1.z); af[7] = (short)f2bf(a1.w);

            const bf16x8 b0 = *(const bf16x8*)&Wb[(((0*4+kk)*4+q)*16 + col)*8];
            const bf16x8 b1 = *(const bf16x8*)&Wb[(((1*4+kk)*4+q)*16 + col)*8];
            const bf16x8 b2 = *(const bf16x8*)&Wb[(((2*4+kk)*4+q)*16 + col)*8];
            const bf16x8 b3 = *(const bf16x8*)&Wb[(((3*4+kk)*4+q)*16 + col)*8];
            acc0 = __builtin_amdgcn_mfma_f32_16x16x32_bf16(af, b0, acc0, 0, 0, 0);
            acc1 = __builtin_amdgcn_mfma_f32_16x16x32_bf16(af, b1, acc1, 0, 0, 0);
            acc2 = __builtin_amdgcn_mfma_f32_16x16x32_bf16(af, b2, acc2, 0, 0, 0);
            acc3 = __builtin_amdgcn_mfma_f32_16x16x32_bf16(af, b3, acc3, 0, 0, 0);
        }

        #pragma unroll
        for (int m = 0; m < 4; ++m) {
            const size_t rb = (size_t)(n0 + q * 4 + m) * 64;
            featb[rb + 0 * 16 + col] = f2bf(acc0[m]);
            featb[rb + 1 * 16 + col] = f2bf(acc1[m]);
            featb[rb + 2 * 16 + col] = f2bf(acc2[m]);
            featb[rb + 3 * 16 + col] = f2bf(acc3[m]);
        }

        #pragma unroll
        for (int m = 0; m < 4; ++m) {
            float pl0 = acc0[m] * alv[0], pr0 = acc0[m] * arv[0];
            float pl1 = acc1[m] * alv[1], pr1 = acc1[m] * arv[1];
            float pl2 = acc2[m] * alv[2], pr2 = acc2[m] * arv[2];
            float pl3 = acc3[m] * alv[3], pr3 = acc3[m] * arv[3];
            #pragma unroll
            for (int off = 8; off >= 1; off >>= 1) {
                pl0 += __shfl_xor(pl0, off); pr0 += __shfl_xor(pr0, off);
                pl1 += __shfl_xor(pl1, off); pr1 += __shfl_xor(pr1, off);
                pl2 += __shfl_xor(pl2, off); pr2 += __shfl_xor(pr2, off);
                pl3 += __shfl_xor(pl3, off); pr3 += __shfl_xor(pr3, off);
            }
            if (col == 0) {
                const size_t eb = (size_t)(n0 + q * 4 + m) * 4;
                el[eb + 0] = pl0; el[eb + 1] = pl1; el[eb + 2] = pl2; el[eb + 3] = pl3;
                er[eb + 0] = pr0; er[eb + 1] = pr1; er[eb + 2] = pr2; er[eb + 3] = pr3;
            }
        }
    }
}

// ---------------------------------------------------------------------------
// fhist: per-half fine histogram (2x782), one LDS atomic per edge, int4 loads.
// ---------------------------------------------------------------------------
__global__ __launch_bounds__(256) void fhist(
    const int* __restrict__ dst,
    int* __restrict__ hhtot)          // 2*NB: per-half fine totals
{
    __shared__ int h[2 * NB];
    const int tid = threadIdx.x;
    for (int i = tid; i < 2 * NB; i += 256) h[i] = 0;
    __syncthreads();
    const int stride = NHIST * 256;
    const int n4 = N_EDGES / 4;           // 800000
    for (int idx = blockIdx.x * 256 + tid; idx < n4; idx += stride) {
        const int4 d4 = ((const int4*)dst)[idx];
        const int off = (idx * 4 >= E0) ? NB : 0;   // E0 % 4 == 0
        atomicAdd(&h[off + (d4.x >> 7)], 1);
        atomicAdd(&h[off + (d4.y >> 7)], 1);
        atomicAdd(&h[off + (d4.z >> 7)], 1);
        atomicAdd(&h[off + (d4.w >> 7)], 1);
    }
    __syncthreads();
    for (int i = tid; i < 2 * NB; i += 256)
        if (h[i]) atomicAdd(&hhtot[i], h[i]);
}

// ---------------------------------------------------------------------------
// Scan: fine base/cursor (782, sum of halves) + per-half coarse base/cursor.
// ---------------------------------------------------------------------------
__global__ __launch_bounds__(64) void bscan(const int* __restrict__ hhtot,
                                            int* __restrict__ base,
                                            int* __restrict__ fcursor,
                                            int* __restrict__ cbaseH,
                                            int* __restrict__ ccursorH)
{
    const int lane = threadIdx.x;
    int carry = 0;
    for (int ch = 0; ch < NB; ch += 64) {
        const int idx = ch + lane;
        const int v = (idx < NB) ? (hhtot[idx] + hhtot[NB + idx]) : 0;
        int x = v;
        #pragma unroll
        for (int off = 1; off < 64; off <<= 1) {
            int y = __shfl_up(x, off);
            if (lane >= off) x += y;
        }
        const int excl = x - v + carry;
        if (idx < NB) { base[idx] = excl; fcursor[idx] = excl; }
        carry += __shfl(x, 63);
    }
    if (lane == 0) base[NB] = carry;

    for (int h2 = 0; h2 < 2; ++h2) {
        int v = 0;
        if (lane < NBC) {
            const int f0 = lane * 32;
            const int f1 = min(f0 + 32, NB);
            for (int f = f0; f < f1; ++f) v += hhtot[h2 * NB + f];
        }
        int x = v;
        #pragma unroll
        for (int off = 1; off < 64; off <<= 1) {
            int y = __shfl_up(x, off);
            if (lane >= off) x += y;
        }
        const int excl = x - v;
        if (lane <= NBC) cbaseH[h2 * (NBC + 1) + lane] = excl;  // lane==NBC -> total
        if (lane < NBC) ccursorH[h2 * NBC + lane] = excl;
    }
}

// ---------------------------------------------------------------------------
// passA body: sigma-path + coarse scatter (25 buckets, runs ~164 edges).
// ---------------------------------------------------------------------------
__device__ __forceinline__ void passA_body(
    unsigned char* smem,
    const int* __restrict__ src,
    const int* __restrict__ dst,
    const float* __restrict__ edge_feat,
    const float* __restrict__ We,
    const float* __restrict__ el,
    const float* __restrict__ er,
    int* __restrict__ ccursorH,
    uint3* __restrict__ wA,
    int half, int blk)
{
    int* ldst  = (int*)smem;              // 16384 B
    int* lbase = (int*)(smem + 16384);    //   100 B
    int* lcnt  = (int*)(smem + 16512);    //   100 B
    const int tid = threadIdx.x;
    if (tid < NBC) lcnt[tid] = 0;
    __syncthreads();
    const int hbeg = half ? E0 : 0;
    const int hend = half ? N_EDGES : E0;
    const int e0 = hbeg + blk * CHA;
    const int n = min(CHA, hend - e0);
    for (int i = tid; i < n; i += 1024) {
        const int d = dst[e0 + i];
        ldst[i] = d;
        atomicAdd(&lcnt[d >> 12], 1);
    }
    __syncthreads();
    if (tid < NBC) {
        const int c = lcnt[tid];
        lbase[tid] = c ? atomicAdd(&ccursorH[half * NBC + tid], c) : 0;
        lcnt[tid] = 0;
    }
    __syncthreads();

    const float4 W0 = ((const float4*)We)[0];
    const float4 W1 = ((const float4*)We)[1];
    const float4 W2 = ((const float4*)We)[2];
    const float4 W3 = ((const float4*)We)[3];

    for (int i = tid; i < n; i += 1024) {
        const int e = e0 + i;
        const int d = ldst[i];
        const int cb = d >> 12;
        const int r = atomicAdd(&lcnt[cb], 1);
        const int pos = lbase[cb] + r;

        const int s = src[e];
        const float4 ef = ((const float4*)edge_feat)[e];
        const float4 l4 = ((const float4*)el)[s];
        const float4 r4 = ((const float4*)er)[d];

        float t0 = l4.x + r4.x; t0 = t0 > 0.f ? t0 : 0.2f * t0;
        float t1 = l4.y + r4.y; t1 = t1 > 0.f ? t1 : 0.2f * t1;
        float t2 = l4.z + r4.z; t2 = t2 > 0.f ? t2 : 0.2f * t2;
        float t3 = l4.w + r4.w; t3 = t3 > 0.f ? t3 : 0.2f * t3;

        const float ee0 = __expf(t0 * (W0.x * ef.x + W0.y * ef.y + W0.z * ef.z + W0.w * ef.w));
        const float ee1 = __expf(t1 * (W1.x * ef.x + W1.y * ef.y + W1.z * ef.z + W1.w * ef.w));
        const float ee2 = __expf(t2 * (W2.x * ef.x + W2.y * ef.y + W2.z * ef.z + W2.w * ef.w));
        const float ee3 = __expf(t3 * (W3.x * ef.x + W3.y * ef.y + W3.z * ef.z + W3.w * ef.w));

        const unsigned h0 = __half_as_ushort(__float2half_rn(ee0));
        const unsigned h1 = __half_as_ushort(__float2half_rn(ee1));
        const unsigned h2 = __half_as_ushort(__float2half_rn(ee2));
        const unsigned h3 = __half_as_ushort(__float2half_rn(ee3));

        wA[pos] = make_uint3((unsigned)s | ((unsigned)(d & (CNODES - 1)) << 17),
                             h0 | (h1 << 16), h2 | (h3 << 16));
    }
}

// ---------------------------------------------------------------------------
// passB body: pure permutation coarse -> fine (782). dst12 has 12 bits.
// ---------------------------------------------------------------------------
__device__ __forceinline__ void passB_body(
    unsigned char* smem,
    const int* __restrict__ cbaseH,
    int* __restrict__ fcursor,
    const uint3* __restrict__ wA,
    uint3* __restrict__ wB,
    int half, int blk)
{
    int* lcb   = (int*)smem;                        //   104 B
    int* lbase = (int*)(smem + 112);                //  3128 B
    int* lcnt  = (int*)(smem + 3240);               //  3128 B
    unsigned short* sfid = (unsigned short*)(smem + 6368);  //  8192 B
    uint3* sx  = (uint3*)(smem + 14576);            // 49152 B  (total 63728)
    const int tid = threadIdx.x;
    for (int i = tid; i < NB; i += 1024) lcnt[i] = 0;
    if (tid < NBC + 1) lcb[tid] = cbaseH[half * (NBC + 1) + tid];
    __syncthreads();

    const int hsz = half ? E1REM : E0;
    const int p0 = blk * CHB;
    const int n = min(CHB, hsz - p0);
    for (int i = tid; i < n; i += 1024) {
        const uint3 x = wA[p0 + i];
        sx[i] = x;
        const int pos = p0 + i;
        int lo = 0, hi = NBC;             // invariant: lcb[lo] <= pos < lcb[hi]
        while (lo + 1 < hi) {
            const int mid = (lo + hi) >> 1;
            if (lcb[mid] <= pos) lo = mid; else hi = mid;
        }
        const int dst12 = (int)((x.x >> 17) & (CNODES - 1));
        const int fid = lo * 32 + (dst12 >> 7);
        sfid[i] = (unsigned short)fid;
        atomicAdd(&lcnt[fid], 1);
    }
    __syncthreads();
    for (int b = tid; b < NB; b += 1024) {
        const int c = lcnt[b];
        lbase[b] = c ? atomicAdd(&fcursor[b], c) : 0;
        lcnt[b] = 0;
    }
    __syncthreads();
    for (int i = tid; i < n; i += 1024) {
        const uint3 x = sx[i];
        const int fid = sfid[i];
        const int r = atomicAdd(&lcnt[fid], 1);
        const unsigned dl = (x.x >> 17) & (BUCKET_NODES - 1);
        wB[lbase[fid] + r] = make_uint3((x.x & 0x1FFFFu) | (dl << 17), x.y, x.z);
    }
}

// ---------------------------------------------------------------------------
// Sequential pass kernels (halves share the d_out-backed wA buffer).
// ---------------------------------------------------------------------------
__global__ __launch_bounds__(1024) void passA(
    const int* __restrict__ src, const int* __restrict__ dst,
    const float* __restrict__ edge_feat, const float* __restrict__ We,
    const float* __restrict__ el, const float* __restrict__ er,
    int* __restrict__ ccursorH, uint3* __restrict__ wA, int half)
{
    __shared__ __align__(16) unsigned char smem[16640];
    passA_body(smem, src, dst, edge_feat, We, el, er, ccursorH, wA, half, blockIdx.x);
}

__global__ __launch_bounds__(1024) void passB(
    const int* __restrict__ cbaseH, int* __restrict__ fcursor,
    const uint3* __restrict__ wA, uint3* __restrict__ wB, int half)
{
    __shared__ __align__(16) unsigned char smem[63728];
    passB_body(smem, cbaseH, fcursor, wA, wB, half, blockIdx.x);
}

// ---------------------------------------------------------------------------
// Finesort: one block (1024 threads) per fine bucket. Counting-sort by
// dst-local IN PLACE, emit per-node CSR offsets. Output payload x is the
// PRE-SCALED featb byte offset (si*128).
// ---------------------------------------------------------------------------
__global__ __launch_bounds__(1024) void finesort(
    const int* __restrict__ base,
    uint3* __restrict__ wP,
    int* __restrict__ node_off)
{
    __shared__ uint3 sP[FS_CAP];          // 54 KB
    __shared__ int hist[BUCKET_NODES];
    __shared__ int cur[BUCKET_NODES];
    const int b = blockIdx.x;
    const int s = base[b];
    int cnt = base[b + 1] - s;
    if (cnt > FS_CAP) cnt = FS_CAP;   // unreachable; safety
    const int tid = threadIdx.x;
    if (tid < BUCKET_NODES) hist[tid] = 0;
    __syncthreads();
    for (int i = tid; i < cnt; i += 1024) {
        const uint3 p = wP[s + i];
        sP[i] = p;
        atomicAdd(&hist[(p.x >> 17) & (BUCKET_NODES - 1)], 1);
    }
    __syncthreads();
    if (tid < 64) {
        int carry = 0;
        for (int ch = 0; ch < BUCKET_NODES; ch += 64) {
            const int v = hist[ch + tid];
            int x = v;
            #pragma unroll
            for (int off = 1; off < 64; off <<= 1) {
                int y = __shfl_up(x, off);
                if (tid >= off) x += y;
            }
            const int excl = x - v + carry;
            cur[ch + tid] = excl;
            const int node = b * BUCKET_NODES + ch + tid;
            if (node < N_NODES) node_off[node] = s + excl;
            carry += __shfl(x, 63);
        }
        if (tid == 0 && b == NB - 1) node_off[N_NODES] = N_EDGES;
    }
    __syncthreads();
    for (int i = tid; i < cnt; i += 1024) {
        const uint3 p = sP[i];
        const int dl = (p.x >> 17) & (BUCKET_NODES - 1);
        const int r = atomicAdd(&cur[dl], 1);
        // emit pre-scaled byte offset: si*128 (si = x & 0x1FFFF -> fits 2^24)
        wP[s + r] = make_uint3((p.x & 0x1FFFFu) << 7, p.y, p.z);
    }
}

// ---------------------------------------------------------------------------
// Aggregate v5 (R17-proven): one wave per dst node, split-wave 2 edges/iter.
// ---------------------------------------------------------------------------
__global__ __launch_bounds__(256) void aggregate(
    const int* __restrict__ node_off,
    const uint3* __restrict__ wP,
    const unsigned short* __restrict__ featb,
    float* __restrict__ rst)
{
    __shared__ float lee[4][64][4];   // [wave][edge][c]   16 KB
    __shared__ unsigned lsi[4][64];   // pre-scaled byte offsets  1 KB
    const int tid = threadIdx.x;
    const int node = (int)((blockIdx.x * 256 + tid) >> 6);
    const int lane = tid & 63;
    const int w = tid >> 6;
    if (node >= N_NODES) return;
    const int half = lane >> 5;                   // which edge of the pair
    const int j = lane & 31;                      // feature-pair index
    const int cc = j >> 3;                        // channel of features 2j,2j+1
    const unsigned jByte = (unsigned)j * 4u;      // byte offset of pair in row
    const unsigned char* __restrict__ fbyte = (const unsigned char*)featb;

    const int start = node_off[node];
    const int end = node_off[node + 1];

    float acc0 = 0.f, acc1 = 0.f;
    float s0 = 0.f, s1 = 0.f, s2 = 0.f, s3 = 0.f;

    for (int bat = start; bat < end; bat += 64) {
        const int n = min(64, end - bat);
        if (lane < n) {
            const uint3 p = wP[bat + lane];
            const float e0 = __half2float(__ushort_as_half((unsigned short)(p.y & 0xffffu)));
            const float e1 = __half2float(__ushort_as_half((unsigned short)(p.y >> 16)));
            const float e2 = __half2float(__ushort_as_half((unsigned short)(p.z & 0xffffu)));
            const float e3 = __half2float(__ushort_as_half((unsigned short)(p.z >> 16)));
            lsi[w][lane] = p.x;                    // si*128 (pre-scaled)
            *(float4*)&lee[w][lane][0] = make_float4(e0, e1, e2, e3);
            s0 += e0; s1 += e1; s2 += e2; s3 += e3;
        } else {
            lsi[w][lane] = 0;
            *(float4*)&lee[w][lane][0] = make_float4(0.f, 0.f, 0.f, 0.f);
        }
        __builtin_amdgcn_wave_barrier();   // keep LDS write->read in program order
        const int iters = (n + 1) >> 1;
        for (int i = 0; i < iters; ++i) {
            const int e = 2 * i + half;            // my half's edge (zeroed if >= n)
            const unsigned so = lsi[w][e];
            const float eec = lee[w][e][cc];
            const unsigned fr = *(const unsigned*)(fbyte + so + jByte);
            acc0 = fmaf(eec, bf2f((unsigned short)(fr & 0xffffu)), acc0);
            acc1 = fmaf(eec, bf2f((unsigned short)(fr >> 16)), acc1);
        }
        __builtin_amdgcn_wave_barrier();   // WAR: next batch overwrites lee
    }

    // merge halves (even-edge + odd-edge partial sums)
    acc0 += __shfl_xor(acc0, 32);
    acc1 += __shfl_xor(acc1, 32);

    #pragma unroll
    for (int off = 32; off >= 1; off >>= 1) {
        s0 += __shfl_xor(s0, off);
        s1 += __shfl_xor(s1, off);
        s2 += __shfl_xor(s2, off);
        s3 += __shfl_xor(s3, off);
    }

    // redistribute: lane l takes feature l = 2*(l>>1) + (l&1) from lane l>>1
    const float v0 = __shfl(acc0, lane >> 1);
    const float v1 = __shfl(acc1, lane >> 1);
    const float accL = (lane & 1) ? v1 : v0;
    const int c = lane >> 4;
    const float ssum = (c == 0) ? s0 : ((c == 1) ? s1 : ((c == 2) ? s2 : s3));
    rst[(size_t)node * 64 + lane] = (end > start) ? accL / ssum : 0.f;
}

// ---------------------------------------------------------------------------
extern "C" void kernel_launch(void* const* d_in, const int* in_sizes, int n_in,
                              void* d_out, int out_size, void* d_ws, size_t ws_size,
                              hipStream_t stream)
{
    const float* node_feat = (const float*)d_in[0];
    const float* edge_feat = (const float*)d_in[1];
    const int*   src       = (const int*)d_in[2];
    const int*   dst       = (const int*)d_in[3];
    const float* Wfc       = (const float*)d_in[4];
    const float* We        = (const float*)d_in[5];
    const float* attn_l    = (const float*)d_in[6];
    const float* attn_r    = (const float*)d_in[7];
    float* rst = (float*)d_out;

    char* ws = (char*)d_ws;
    unsigned short* featb = (unsigned short*)(ws);        // 12,800,000 B
    float* el       = (float*)(ws + 12800000);            //  1,600,000 B
    float* er       = (float*)(ws + 14400000);            //  1,600,000 B
    int*   hhtot    = (int*)  (ws + 16000000);            //      6,256 B
    int*   base     = (int*)  (ws + 16006400);            //      3,132 B
    int*   fcursor  = (int*)  (ws + 16009600);            //      3,128 B
    int*   cbaseH   = (int*)  (ws + 16012800);            //        208 B
    int*   ccursorH = (int*)  (ws + 16013056);            //        200 B
    int*   node_off = (int*)  (ws + 16013312);            //    400,004 B
    uint3* wB       = (uint3*)(ws + 16413952);            // 38,400,000 B
                                                          // total ~54.8 MB
    // d_out doubles as the per-half pass-A payload buffer (<=19.3 MB of 25.6);
    // halves are processed SEQUENTIALLY (A0,B0,A1,B1) because they share it.
    uint3* wA = (uint3*)d_out;

    hipMemsetAsync(hhtot, 0, 2 * NB * sizeof(int), stream);

    node_proj<<<NPROJ, 256, 0, stream>>>(node_feat, Wfc, attn_l, attn_r, featb, el, er);
    fhist<<<NHIST, 256, 0, stream>>>(dst, hhtot);
    bscan<<<1, 64, 0, stream>>>(hhtot, base, fcursor, cbaseH, ccursorH);

    passA<<<NPA0, 1024, 0, stream>>>(src, dst, edge_feat, We, el, er, ccursorH, wA, 0);
    passB<<<NPB0, 1024, 0, stream>>>(cbaseH, fcursor, wA, wB, 0);
    passA<<<NPA1, 1024, 0, stream>>>(src, dst, edge_feat, We, el, er, ccursorH, wA, 1);
    passB<<<NPB1, 1024, 0, stream>>>(cbaseH, fcursor, wA, wB, 1);

    finesort<<<NB, 1024, 0, stream>>>(base, wB, node_off);
    aggregate<<<(N_NODES * 64 + 255) / 256, 256, 0, stream>>>(node_off, wB, featb, rst);
}

// Round 26
// 231.302 us; speedup vs baseline: 1.1712x; 1.0414x over previous
//
#include <hip/hip_runtime.h>
#include <hip/hip_fp16.h>

#define N_NODES 100000
#define N_EDGES 3200000
#define E0 1601536        // half boundary = 391*4096 (CHA-aligned, div by 4)
#define E1REM 1598464     // N_EDGES - E0
#define BUCKET_NODES 128
#define NB 782            // fine buckets (128 dst nodes each)
#define NBC 25            // coarse buckets (4096 nodes each)
#define CNODES 4096
#define CHA 4096          // pass-A chunk: runs ~164 edges (~2 KB)
#define NPA0 391
#define NPA1 391
#define CHB 4096
#define NPB0 391
#define NPB1 391
#define FS_CAP 4608       // bucket LDS capacity (mean 4096, +8 sigma)
#define NPROJ 782
#define NG64 1563
#define NHIST 512

typedef __attribute__((ext_vector_type(8))) short bf16x8;
typedef __attribute__((ext_vector_type(4))) float f32x4;

__device__ __forceinline__ unsigned short f2bf(float f) {
    unsigned u = __float_as_uint(f);
    unsigned r = (u + 0x7FFFu + ((u >> 16) & 1u)) >> 16;   // RNE
    return (unsigned short)r;
}
__device__ __forceinline__ float bf2f(unsigned short h) {
    return __uint_as_float(((unsigned)h) << 16);
}

// ---------------------------------------------------------------------------
// node_proj (MFMA, R22-proven)
// ---------------------------------------------------------------------------
__global__ __launch_bounds__(256) void node_proj(
    const float* __restrict__ node_feat,
    const float* __restrict__ Wfc,
    const float* __restrict__ attn_l,
    const float* __restrict__ attn_r,
    unsigned short* __restrict__ featb,
    float* __restrict__ el,
    float* __restrict__ er)
{
    __shared__ short Wb[8192];          // 16 KB bf16, fragment-linear
    const int tid = threadIdx.x;
    for (int i = tid; i < 8192; i += 256) {
        const int e   = i & 7;
        const int col = (i >> 3) & 15;
        const int q   = (i >> 7) & 3;
        const int kk  = (i >> 9) & 3;
        const int t   = (i >> 11) & 3;
        Wb[i] = (short)f2bf(Wfc[(t * 16 + col) * 128 + kk * 32 + q * 8 + e]);
    }
    __syncthreads();

    const int lane = tid & 63;
    const int w = tid >> 6;
    const int col = lane & 15;
    const int q = lane >> 4;

    float alv[4], arv[4];
    #pragma unroll
    for (int t = 0; t < 4; ++t) {
        alv[t] = attn_l[t * 16 + col];
        arv[t] = attn_r[t * 16 + col];
    }

    for (int g = blockIdx.x; g < NG64; g += NPROJ) {
        const int n0 = g * 64 + w * 16;
        if (n0 >= N_NODES) continue;

        f32x4 acc0 = {0.f,0.f,0.f,0.f}, acc1 = {0.f,0.f,0.f,0.f};
        f32x4 acc2 = {0.f,0.f,0.f,0.f}, acc3 = {0.f,0.f,0.f,0.f};

        #pragma unroll
        for (int kk = 0; kk < 4; ++kk) {
            const float* ap = node_feat + (size_t)(n0 + col) * 128 + kk * 32 + q * 8;
            const float4 a0 = *(const float4*)ap;
            const float4 a1 = *(const float4*)(ap + 4);
            bf16x8 af;
            af[0] = (short)f2bf(a0.x); af[1] = (short)f2bf(a0.y);
            af[2] = (short)f2bf(a0.z); af[3] = (short)f2bf(a0.w);
            af[4] = (short)f2bf(a1.x); af[5] = (short)f2bf(a1.y);
            af[6] = (short)f2bf(a1.z); af[7] = (short)f2bf(a1.w);

            const bf16x8 b0 = *(const bf16x8*)&Wb[(((0*4+kk)*4+q)*16 + col)*8];
            const bf16x8 b1 = *(const bf16x8*)&Wb[(((1*4+kk)*4+q)*16 + col)*8];
            const bf16x8 b2 = *(const bf16x8*)&Wb[(((2*4+kk)*4+q)*16 + col)*8];
            const bf16x8 b3 = *(const bf16x8*)&Wb[(((3*4+kk)*4+q)*16 + col)*8];
            acc0 = __builtin_amdgcn_mfma_f32_16x16x32_bf16(af, b0, acc0, 0, 0, 0);
            acc1 = __builtin_amdgcn_mfma_f32_16x16x32_bf16(af, b1, acc1, 0, 0, 0);
            acc2 = __builtin_amdgcn_mfma_f32_16x16x32_bf16(af, b2, acc2, 0, 0, 0);
            acc3 = __builtin_amdgcn_mfma_f32_16x16x32_bf16(af, b3, acc3, 0, 0, 0);
        }

        #pragma unroll
        for (int m = 0; m < 4; ++m) {
            const size_t rb = (size_t)(n0 + q * 4 + m) * 64;
            featb[rb + 0 * 16 + col] = f2bf(acc0[m]);
            featb[rb + 1 * 16 + col] = f2bf(acc1[m]);
            featb[rb + 2 * 16 + col] = f2bf(acc2[m]);
            featb[rb + 3 * 16 + col] = f2bf(acc3[m]);
        }

        #pragma unroll
        for (int m = 0; m < 4; ++m) {
            float pl0 = acc0[m] * alv[0], pr0 = acc0[m] * arv[0];
            float pl1 = acc1[m] * alv[1], pr1 = acc1[m] * arv[1];
            float pl2 = acc2[m] * alv[2], pr2 = acc2[m] * arv[2];
            float pl3 = acc3[m] * alv[3], pr3 = acc3[m] * arv[3];
            #pragma unroll
            for (int off = 8; off >= 1; off >>= 1) {
                pl0 += __shfl_xor(pl0, off); pr0 += __shfl_xor(pr0, off);
                pl1 += __shfl_xor(pl1, off); pr1 += __shfl_xor(pr1, off);
                pl2 += __shfl_xor(pl2, off); pr2 += __shfl_xor(pr2, off);
                pl3 += __shfl_xor(pl3, off); pr3 += __shfl_xor(pr3, off);
            }
            if (col == 0) {
                const size_t eb = (size_t)(n0 + q * 4 + m) * 4;
                el[eb + 0] = pl0; el[eb + 1] = pl1; el[eb + 2] = pl2; el[eb + 3] = pl3;
                er[eb + 0] = pr0; er[eb + 1] = pr1; er[eb + 2] = pr2; er[eb + 3] = pr3;
            }
        }
    }
}

// ---------------------------------------------------------------------------
// fhist: per-half fine histogram (2x782)
// ---------------------------------------------------------------------------
__global__ __launch_bounds__(256) void fhist(
    const int* __restrict__ dst,
    int* __restrict__ hhtot)
{
    __shared__ int h[2 * NB];
    const int tid = threadIdx.x;
    for (int i = tid; i < 2 * NB; i += 256) h[i] = 0;
    __syncthreads();
    const int stride = NHIST * 256;
    const int n4 = N_EDGES / 4;
    for (int idx = blockIdx.x * 256 + tid; idx < n4; idx += stride) {
        const int4 d4 = ((const int4*)dst)[idx];
        const int off = (idx * 4 >= E0) ? NB : 0;
        atomicAdd(&h[off + (d4.x >> 7)], 1);
        atomicAdd(&h[off + (d4.y >> 7)], 1);
        atomicAdd(&h[off + (d4.z >> 7)], 1);
        atomicAdd(&h[off + (d4.w >> 7)], 1);
    }
    __syncthreads();
    for (int i = tid; i < 2 * NB; i += 256)
        if (h[i]) atomicAdd(&hhtot[i], h[i]);
}

// ---------------------------------------------------------------------------
// Scan: fine base/cursor (782, sum of halves) + per-half coarse base/cursor.
// ---------------------------------------------------------------------------
__global__ __launch_bounds__(64) void bscan(const int* __restrict__ hhtot,
                                            int* __restrict__ base,
                                            int* __restrict__ fcursor,
                                            int* __restrict__ cbaseH,
                                            int* __restrict__ ccursorH)
{
    const int lane = threadIdx.x;
    int carry = 0;
    for (int ch = 0; ch < NB; ch += 64) {
        const int idx = ch + lane;
        const int v = (idx < NB) ? (hhtot[idx] + hhtot[NB + idx]) : 0;
        int x = v;
        #pragma unroll
        for (int off = 1; off < 64; off <<= 1) {
            int y = __shfl_up(x, off);
            if (lane >= off) x += y;
        }
        const int excl = x - v + carry;
        if (idx < NB) { base[idx] = excl; fcursor[idx] = excl; }
        carry += __shfl(x, 63);
    }
    if (lane == 0) base[NB] = carry;

    for (int h2 = 0; h2 < 2; ++h2) {
        int v = 0;
        if (lane < NBC) {
            const int f0 = lane * 32;
            const int f1 = min(f0 + 32, NB);
            for (int f = f0; f < f1; ++f) v += hhtot[h2 * NB + f];
        }
        int x = v;
        #pragma unroll
        for (int off = 1; off < 64; off <<= 1) {
            int y = __shfl_up(x, off);
            if (lane >= off) x += y;
        }
        const int excl = x - v;
        if (lane <= NBC) cbaseH[h2 * (NBC + 1) + lane] = excl;
        if (lane < NBC) ccursorH[h2 * NBC + lane] = excl;
    }
}

// ---------------------------------------------------------------------------
// passA body: sigma-path + coarse scatter (25 buckets, runs ~164 edges).
// ---------------------------------------------------------------------------
__device__ __forceinline__ void passA_body(
    unsigned char* smem,
    const int* __restrict__ src,
    const int* __restrict__ dst,
    const float* __restrict__ edge_feat,
    const float* __restrict__ We,
    const float* __restrict__ el,
    const float* __restrict__ er,
    int* __restrict__ ccursorH,
    uint3* __restrict__ wA,
    int half, int blk)
{
    int* ldst  = (int*)smem;              // 16384 B
    int* lbase = (int*)(smem + 16384);    //   100 B
    int* lcnt  = (int*)(smem + 16512);    //   100 B
    const int tid = threadIdx.x;
    if (tid < NBC) lcnt[tid] = 0;
    __syncthreads();
    const int hbeg = half ? E0 : 0;
    const int hend = half ? N_EDGES : E0;
    const int e0 = hbeg + blk * CHA;
    const int n = min(CHA, hend - e0);
    for (int i = tid; i < n; i += 1024) {
        const int d = dst[e0 + i];
        ldst[i] = d;
        atomicAdd(&lcnt[d >> 12], 1);
    }
    __syncthreads();
    if (tid < NBC) {
        const int c = lcnt[tid];
        lbase[tid] = c ? atomicAdd(&ccursorH[half * NBC + tid], c) : 0;
        lcnt[tid] = 0;
    }
    __syncthreads();

    const float4 W0 = ((const float4*)We)[0];
    const float4 W1 = ((const float4*)We)[1];
    const float4 W2 = ((const float4*)We)[2];
    const float4 W3 = ((const float4*)We)[3];

    for (int i = tid; i < n; i += 1024) {
        const int e = e0 + i;
        const int d = ldst[i];
        const int cb = d >> 12;
        const int r = atomicAdd(&lcnt[cb], 1);
        const int pos = lbase[cb] + r;

        const int s = src[e];
        const float4 ef = ((const float4*)edge_feat)[e];
        const float4 l4 = ((const float4*)el)[s];
        const float4 r4 = ((const float4*)er)[d];

        float t0 = l4.x + r4.x; t0 = t0 > 0.f ? t0 : 0.2f * t0;
        float t1 = l4.y + r4.y; t1 = t1 > 0.f ? t1 : 0.2f * t1;
        float t2 = l4.z + r4.z; t2 = t2 > 0.f ? t2 : 0.2f * t2;
        float t3 = l4.w + r4.w; t3 = t3 > 0.f ? t3 : 0.2f * t3;

        const float ee0 = __expf(t0 * (W0.x * ef.x + W0.y * ef.y + W0.z * ef.z + W0.w * ef.w));
        const float ee1 = __expf(t1 * (W1.x * ef.x + W1.y * ef.y + W1.z * ef.z + W1.w * ef.w));
        const float ee2 = __expf(t2 * (W2.x * ef.x + W2.y * ef.y + W2.z * ef.z + W2.w * ef.w));
        const float ee3 = __expf(t3 * (W3.x * ef.x + W3.y * ef.y + W3.z * ef.z + W3.w * ef.w));

        const unsigned h0 = __half_as_ushort(__float2half_rn(ee0));
        const unsigned h1 = __half_as_ushort(__float2half_rn(ee1));
        const unsigned h2 = __half_as_ushort(__float2half_rn(ee2));
        const unsigned h3 = __half_as_ushort(__float2half_rn(ee3));

        wA[pos] = make_uint3((unsigned)s | ((unsigned)(d & (CNODES - 1)) << 17),
                             h0 | (h1 << 16), h2 | (h3 << 16));
    }
}

// ---------------------------------------------------------------------------
// passB body: pure permutation coarse -> fine (782).
// ---------------------------------------------------------------------------
__device__ __forceinline__ void passB_body(
    unsigned char* smem,
    const int* __restrict__ cbaseH,
    int* __restrict__ fcursor,
    const uint3* __restrict__ wA,
    uint3* __restrict__ wB,
    int half, int blk)
{
    int* lcb   = (int*)smem;                        //   104 B
    int* lbase = (int*)(smem + 112);                //  3128 B
    int* lcnt  = (int*)(smem + 3240);               //  3128 B
    unsigned short* sfid = (unsigned short*)(smem + 6368);  //  8192 B
    uint3* sx  = (uint3*)(smem + 14576);            // 49152 B
    const int tid = threadIdx.x;
    for (int i = tid; i < NB; i += 1024) lcnt[i] = 0;
    if (tid < NBC + 1) lcb[tid] = cbaseH[half * (NBC + 1) + tid];
    __syncthreads();

    const int hsz = half ? E1REM : E0;
    const int p0 = blk * CHB;
    const int n = min(CHB, hsz - p0);
    for (int i = tid; i < n; i += 1024) {
        const uint3 x = wA[p0 + i];
        sx[i] = x;
        const int pos = p0 + i;
        int lo = 0, hi = NBC;
        while (lo + 1 < hi) {
            const int mid = (lo + hi) >> 1;
            if (lcb[mid] <= pos) lo = mid; else hi = mid;
        }
        const int dst12 = (int)((x.x >> 17) & (CNODES - 1));
        const int fid = lo * 32 + (dst12 >> 7);
        sfid[i] = (unsigned short)fid;
        atomicAdd(&lcnt[fid], 1);
    }
    __syncthreads();
    for (int b = tid; b < NB; b += 1024) {
        const int c = lcnt[b];
        lbase[b] = c ? atomicAdd(&fcursor[b], c) : 0;
        lcnt[b] = 0;
    }
    __syncthreads();
    for (int i = tid; i < n; i += 1024) {
        const uint3 x = sx[i];
        const int fid = sfid[i];
        const int r = atomicAdd(&lcnt[fid], 1);
        const unsigned dl = (x.x >> 17) & (BUCKET_NODES - 1);
        wB[lbase[fid] + r] = make_uint3((x.x & 0x1FFFFu) | (dl << 17), x.y, x.z);
    }
}

__global__ __launch_bounds__(1024) void passA(
    const int* __restrict__ src, const int* __restrict__ dst,
    const float* __restrict__ edge_feat, const float* __restrict__ We,
    const float* __restrict__ el, const float* __restrict__ er,
    int* __restrict__ ccursorH, uint3* __restrict__ wA, int half)
{
    __shared__ __align__(16) unsigned char smem[16640];
    passA_body(smem, src, dst, edge_feat, We, el, er, ccursorH, wA, half, blockIdx.x);
}

__global__ __launch_bounds__(1024) void passB(
    const int* __restrict__ cbaseH, int* __restrict__ fcursor,
    const uint3* __restrict__ wA, uint3* __restrict__ wB, int half)
{
    __shared__ __align__(16) unsigned char smem[63728];
    passB_body(smem, cbaseH, fcursor, wA, wB, half, blockIdx.x);
}

// ---------------------------------------------------------------------------
// sort_agg: FUSED finesort + aggregate. One block (1024 thr) per fine bucket.
// Phase 1: stage payload SoA into LDS (sA = src|dl, sE = ee fp16x4) + hist.
// Phase 2: scan -> off/cur. Phase 3: counting-RANK (inv[sortedpos]=origidx,
// no payload movement); same thread pre-scales sA[i] to byte offset.
// Phase 4: wave w aggregates nodes w*8..w*8+7 straight from LDS
// (split-wave 2 edges/iter, per-lane channel ssum), writes rst once.
// Deletes: sorted-payload global write+re-read (77 MB), node_off, staging.
// LDS 66 KB -> 2 blocks/CU (132 <= 160 KB), 32 waves/CU.
// ---------------------------------------------------------------------------
__global__ __launch_bounds__(1024) void sort_agg(
    const int* __restrict__ base,
    const uint3* __restrict__ wP,
    const unsigned short* __restrict__ featb,
    float* __restrict__ rst)
{
    __shared__ unsigned sA[FS_CAP];           // 18432 B  (then: (src*128))
    __shared__ unsigned sE[FS_CAP * 2];       // 36864 B  (ee01, ee23 fp16x2)
    __shared__ unsigned short inv[FS_CAP];    //  9216 B  sorted pos -> orig idx
    __shared__ int hist[BUCKET_NODES];        //    512 B
    __shared__ int off[BUCKET_NODES + 1];     //    516 B
    __shared__ int cur[BUCKET_NODES];         //    512 B
    const int b = blockIdx.x;
    const int s = base[b];
    int cnt = base[b + 1] - s;
    if (cnt > FS_CAP) cnt = FS_CAP;   // unreachable; safety
    const int tid = threadIdx.x;
    if (tid < BUCKET_NODES) hist[tid] = 0;
    __syncthreads();

    for (int i = tid; i < cnt; i += 1024) {
        const uint3 p = wP[s + i];
        sA[i] = p.x;
        sE[2 * i]     = p.y;
        sE[2 * i + 1] = p.z;
        atomicAdd(&hist[(p.x >> 17) & (BUCKET_NODES - 1)], 1);
    }
    __syncthreads();

    if (tid < 64) {
        int carry = 0;
        for (int ch = 0; ch < BUCKET_NODES; ch += 64) {
            const int v = hist[ch + tid];
            int x = v;
            #pragma unroll
            for (int o = 1; o < 64; o <<= 1) {
                int y = __shfl_up(x, o);
                if (tid >= o) x += y;
            }
            const int excl = x - v + carry;
            off[ch + tid] = excl;
            cur[ch + tid] = excl;
            carry += __shfl(x, 63);
        }
        if (tid == 0) off[BUCKET_NODES] = carry;   // == cnt
    }
    __syncthreads();

    for (int i = tid; i < cnt; i += 1024) {
        const unsigned a = sA[i];
        const int dl = (int)((a >> 17) & (BUCKET_NODES - 1));
        const int r = atomicAdd(&cur[dl], 1);
        inv[r] = (unsigned short)i;
        sA[i] = (a & 0x1FFFFu) << 7;        // pre-scale to featb byte offset
    }
    __syncthreads();

    // -------- aggregation from LDS --------
    const int lane = tid & 63;
    const int w = tid >> 6;
    const int half = lane >> 5;               // which edge of the pair
    const int j = lane & 31;                  // feature-pair index
    const int cc = j >> 3;                    // channel of features 2j,2j+1
    const unsigned jByte = (unsigned)j * 4u;
    const unsigned char* __restrict__ fbyte = (const unsigned char*)featb;
    const int node0 = b * BUCKET_NODES;

    #pragma unroll 1
    for (int nn = 0; nn < 8; ++nn) {
        const int nl = w * 8 + nn;
        const int node = node0 + nl;
        if (node >= N_NODES) break;
        const int st = off[nl];
        const int deg = off[nl + 1] - st;

        float acc0 = 0.f, acc1 = 0.f, scc = 0.f;
        const int iters = (deg + 1) >> 1;
        for (int i = 0; i < iters; ++i) {
            const int o = 2 * i + half;
            const bool valid = o < deg;
            const int pos = valid ? (st + o) : 0;   // clamp: bucket pos 0 valid when deg>0
            const int idx = (int)inv[pos];
            const unsigned so = sA[idx];
            const unsigned ed = sE[2 * idx + (cc >> 1)];
            float eec = __half2float(__ushort_as_half(
                (unsigned short)((cc & 1) ? (ed >> 16) : (ed & 0xffffu))));
            if (!valid) eec = 0.f;
            const unsigned fr = *(const unsigned*)(fbyte + so + jByte);
            acc0 = fmaf(eec, bf2f((unsigned short)(fr & 0xffffu)), acc0);
            acc1 = fmaf(eec, bf2f((unsigned short)(fr >> 16)), acc1);
            scc += eec;
        }

        const float a0 = acc0 + __shfl_xor(acc0, 32);
        const float a1 = acc1 + __shfl_xor(acc1, 32);
        const float ss = scc + __shfl_xor(scc, 32);

        // redistribute: lane l takes feature l from source lane l>>1
        const float v0 = __shfl(a0, lane >> 1);
        const float v1 = __shfl(a1, lane >> 1);
        const float sv = __shfl(ss, lane >> 1);
        const float accL = (lane & 1) ? v1 : v0;
        rst[(size_t)node * 64 + lane] = (deg > 0) ? accL / sv : 0.f;
    }
}

// ---------------------------------------------------------------------------
extern "C" void kernel_launch(void* const* d_in, const int* in_sizes, int n_in,
                              void* d_out, int out_size, void* d_ws, size_t ws_size,
                              hipStream_t stream)
{
    const float* node_feat = (const float*)d_in[0];
    const float* edge_feat = (const float*)d_in[1];
    const int*   src       = (const int*)d_in[2];
    const int*   dst       = (const int*)d_in[3];
    const float* Wfc       = (const float*)d_in[4];
    const float* We        = (const float*)d_in[5];
    const float* attn_l    = (const float*)d_in[6];
    const float* attn_r    = (const float*)d_in[7];
    float* rst = (float*)d_out;

    char* ws = (char*)d_ws;
    unsigned short* featb = (unsigned short*)(ws);        // 12,800,000 B
    float* el       = (float*)(ws + 12800000);            //  1,600,000 B
    float* er       = (float*)(ws + 14400000);            //  1,600,000 B
    int*   hhtot    = (int*)  (ws + 16000000);            //      6,256 B
    int*   base     = (int*)  (ws + 16006400);            //      3,132 B
    int*   fcursor  = (int*)  (ws + 16009600);            //      3,128 B
    int*   cbaseH   = (int*)  (ws + 16012800);            //        208 B
    int*   ccursorH = (int*)  (ws + 16013056);            //        200 B
    uint3* wB       = (uint3*)(ws + 16013312);            // 38,400,000 B
                                                          // total ~54.4 MB
    // d_out doubles as the per-half pass-A payload buffer (<=19.3 MB of 25.6);
    // halves are processed SEQUENTIALLY (A0,B0,A1,B1) because they share it.
    uint3* wA = (uint3*)d_out;

    hipMemsetAsync(hhtot, 0, 2 * NB * sizeof(int), stream);

    node_proj<<<NPROJ, 256, 0, stream>>>(node_feat, Wfc, attn_l, attn_r, featb, el, er);
    fhist<<<NHIST, 256, 0, stream>>>(dst, hhtot);
    bscan<<<1, 64, 0, stream>>>(hhtot, base, fcursor, cbaseH, ccursorH);

    passA<<<NPA0, 1024, 0, stream>>>(src, dst, edge_feat, We, el, er, ccursorH, wA, 0);
    passB<<<NPB0, 1024, 0, stream>>>(cbaseH, fcursor, wA, wB, 0);
    passA<<<NPA1, 1024, 0, stream>>>(src, dst, edge_feat, We, el, er, ccursorH, wA, 1);
    passB<<<NPB1, 1024, 0, stream>>>(cbaseH, fcursor, wA, wB, 1);

    sort_agg<<<NB, 1024, 0, stream>>>(base, wB, featb, rst);
}

// Round 27
// 217.683 us; speedup vs baseline: 1.2445x; 1.0626x over previous
//
#include <hip/hip_runtime.h>
#include <hip/hip_fp16.h>

#define N_NODES 100000
#define N_EDGES 3200000
#define E0 1601536        // half boundary = 391*4096 (CHA-aligned, div by 4)
#define E1REM 1598464     // N_EDGES - E0
#define BUCKET_NODES 128
#define NB 782            // fine buckets (128 dst nodes each)
#define NBC 25            // coarse buckets (4096 nodes each)
#define CNODES 4096
#define CHA 4096          // pass-A chunk: runs ~164 edges (~2 KB)
#define NPA0 391
#define NPA1 391
#define CHB 4096
#define NPB0 391
#define NPB1 391
#define FS_CAP 4608       // bucket LDS capacity (mean 4096, +8 sigma)
#define NPROJ 782         // proj blocks (grid-stride over 1563 groups of 64)
#define NG64 1563
#define NHIST 512         // hist blocks (after proj blocks in fused grid)

typedef __attribute__((ext_vector_type(8))) short bf16x8;
typedef __attribute__((ext_vector_type(4))) float f32x4;

__device__ __forceinline__ unsigned short f2bf(float f) {
    unsigned u = __float_as_uint(f);
    unsigned r = (u + 0x7FFFu + ((u >> 16) & 1u)) >> 16;   // RNE
    return (unsigned short)r;
}
__device__ __forceinline__ float bf2f(unsigned short h) {
    return __uint_as_float(((unsigned)h) << 16);
}

// ---------------------------------------------------------------------------
// proj_hist (fused, PROJ FIRST): blocks [0,NPROJ) run the MFMA projection
// (MFMA-pipe-bound, ~25 us, the long pole -> starts at t=0); blocks
// [NPROJ,NPROJ+NHIST) run the per-half fine histogram (LDS-atomic-bound,
// ~15 us) and overlap under it. LDS union: proj 16 KB / hist 6.3 KB.
// ---------------------------------------------------------------------------
__global__ __launch_bounds__(256) void proj_hist(
    const float* __restrict__ node_feat,
    const float* __restrict__ Wfc,
    const float* __restrict__ attn_l,
    const float* __restrict__ attn_r,
    unsigned short* __restrict__ featb,
    float* __restrict__ el,
    float* __restrict__ er,
    const int* __restrict__ dst,
    int* __restrict__ hhtot)
{
    __shared__ __align__(16) unsigned char smem[16384];
    const int tid = threadIdx.x;

    if (blockIdx.x >= NPROJ) {
        // ------------------- histogram part -------------------
        int* h = (int*)smem;                  // 2*NB ints = 6256 B
        for (int i = tid; i < 2 * NB; i += 256) h[i] = 0;
        __syncthreads();
        const int hb = blockIdx.x - NPROJ;
        const int stride = NHIST * 256;
        const int n4 = N_EDGES / 4;           // 800000
        for (int idx = hb * 256 + tid; idx < n4; idx += stride) {
            const int4 d4 = ((const int4*)dst)[idx];
            const int off = (idx * 4 >= E0) ? NB : 0;   // E0 % 4 == 0
            atomicAdd(&h[off + (d4.x >> 7)], 1);
            atomicAdd(&h[off + (d4.y >> 7)], 1);
            atomicAdd(&h[off + (d4.z >> 7)], 1);
            atomicAdd(&h[off + (d4.w >> 7)], 1);
        }
        __syncthreads();
        for (int i = tid; i < 2 * NB; i += 256)
            if (h[i]) atomicAdd(&hhtot[i], h[i]);
        return;
    }

    // ------------------- projection part (MFMA) -------------------
    short* Wb = (short*)smem;           // 16 KB bf16, fragment-linear
    for (int i = tid; i < 8192; i += 256) {
        const int e   = i & 7;
        const int col = (i >> 3) & 15;
        const int q   = (i >> 7) & 3;
        const int kk  = (i >> 9) & 3;
        const int t   = (i >> 11) & 3;
        Wb[i] = (short)f2bf(Wfc[(t * 16 + col) * 128 + kk * 32 + q * 8 + e]);
    }
    __syncthreads();

    const int lane = tid & 63;
    const int w = tid >> 6;
    const int col = lane & 15;
    const int q = lane >> 4;

    float alv[4], arv[4];
    #pragma unroll
    for (int t = 0; t < 4; ++t) {
        alv[t] = attn_l[t * 16 + col];
        arv[t] = attn_r[t * 16 + col];
    }

    for (int g = blockIdx.x; g < NG64; g += NPROJ) {
        const int n0 = g * 64 + w * 16;
        if (n0 >= N_NODES) continue;

        f32x4 acc0 = {0.f,0.f,0.f,0.f}, acc1 = {0.f,0.f,0.f,0.f};
        f32x4 acc2 = {0.f,0.f,0.f,0.f}, acc3 = {0.f,0.f,0.f,0.f};

        #pragma unroll
        for (int kk = 0; kk < 4; ++kk) {
            const float* ap = node_feat + (size_t)(n0 + col) * 128 + kk * 32 + q * 8;
            const float4 a0 = *(const float4*)ap;
            const float4 a1 = *(const float4*)(ap + 4);
            bf16x8 af;
            af[0] = (short)f2bf(a0.x); af[1] = (short)f2bf(a0.y);
            af[2] = (short)f2bf(a0.z); af[3] = (short)f2bf(a0.w);
            af[4] = (short)f2bf(a1.x); af[5] = (short)f2bf(a1.y);
            af[6] = (short)f2bf(a1.z); af[7] = (short)f2bf(a1.w);

            const bf16x8 b0 = *(const bf16x8*)&Wb[(((0*4+kk)*4+q)*16 + col)*8];
            const bf16x8 b1 = *(const bf16x8*)&Wb[(((1*4+kk)*4+q)*16 + col)*8];
            const bf16x8 b2 = *(const bf16x8*)&Wb[(((2*4+kk)*4+q)*16 + col)*8];
            const bf16x8 b3 = *(const bf16x8*)&Wb[(((3*4+kk)*4+q)*16 + col)*8];
            acc0 = __builtin_amdgcn_mfma_f32_16x16x32_bf16(af, b0, acc0, 0, 0, 0);
            acc1 = __builtin_amdgcn_mfma_f32_16x16x32_bf16(af, b1, acc1, 0, 0, 0);
            acc2 = __builtin_amdgcn_mfma_f32_16x16x32_bf16(af, b2, acc2, 0, 0, 0);
            acc3 = __builtin_amdgcn_mfma_f32_16x16x32_bf16(af, b3, acc3, 0, 0, 0);
        }

        #pragma unroll
        for (int m = 0; m < 4; ++m) {
            const size_t rb = (size_t)(n0 + q * 4 + m) * 64;
            featb[rb + 0 * 16 + col] = f2bf(acc0[m]);
            featb[rb + 1 * 16 + col] = f2bf(acc1[m]);
            featb[rb + 2 * 16 + col] = f2bf(acc2[m]);
            featb[rb + 3 * 16 + col] = f2bf(acc3[m]);
        }

        #pragma unroll
        for (int m = 0; m < 4; ++m) {
            float pl0 = acc0[m] * alv[0], pr0 = acc0[m] * arv[0];
            float pl1 = acc1[m] * alv[1], pr1 = acc1[m] * arv[1];
            float pl2 = acc2[m] * alv[2], pr2 = acc2[m] * arv[2];
            float pl3 = acc3[m] * alv[3], pr3 = acc3[m] * arv[3];
            #pragma unroll
            for (int off = 8; off >= 1; off >>= 1) {
                pl0 += __shfl_xor(pl0, off); pr0 += __shfl_xor(pr0, off);
                pl1 += __shfl_xor(pl1, off); pr1 += __shfl_xor(pr1, off);
                pl2 += __shfl_xor(pl2, off); pr2 += __shfl_xor(pr2, off);
                pl3 += __shfl_xor(pl3, off); pr3 += __shfl_xor(pr3, off);
            }
            if (col == 0) {
                const size_t eb = (size_t)(n0 + q * 4 + m) * 4;
                el[eb + 0] = pl0; el[eb + 1] = pl1; el[eb + 2] = pl2; el[eb + 3] = pl3;
                er[eb + 0] = pr0; er[eb + 1] = pr1; er[eb + 2] = pr2; er[eb + 3] = pr3;
            }
        }
    }
}

// ---------------------------------------------------------------------------
// Scan: fine base/cursor (782, sum of halves) + per-half coarse base/cursor.
// ---------------------------------------------------------------------------
__global__ __launch_bounds__(64) void bscan(const int* __restrict__ hhtot,
                                            int* __restrict__ base,
                                            int* __restrict__ fcursor,
                                            int* __restrict__ cbaseH,
                                            int* __restrict__ ccursorH)
{
    const int lane = threadIdx.x;
    int carry = 0;
    for (int ch = 0; ch < NB; ch += 64) {
        const int idx = ch + lane;
        const int v = (idx < NB) ? (hhtot[idx] + hhtot[NB + idx]) : 0;
        int x = v;
        #pragma unroll
        for (int off = 1; off < 64; off <<= 1) {
            int y = __shfl_up(x, off);
            if (lane >= off) x += y;
        }
        const int excl = x - v + carry;
        if (idx < NB) { base[idx] = excl; fcursor[idx] = excl; }
        carry += __shfl(x, 63);
    }
    if (lane == 0) base[NB] = carry;

    for (int h2 = 0; h2 < 2; ++h2) {
        int v = 0;
        if (lane < NBC) {
            const int f0 = lane * 32;
            const int f1 = min(f0 + 32, NB);
            for (int f = f0; f < f1; ++f) v += hhtot[h2 * NB + f];
        }
        int x = v;
        #pragma unroll
        for (int off = 1; off < 64; off <<= 1) {
            int y = __shfl_up(x, off);
            if (lane >= off) x += y;
        }
        const int excl = x - v;
        if (lane <= NBC) cbaseH[h2 * (NBC + 1) + lane] = excl;
        if (lane < NBC) ccursorH[h2 * NBC + lane] = excl;
    }
}

// ---------------------------------------------------------------------------
// passA body: sigma-path + coarse scatter (25 buckets, runs ~164 edges).
// ---------------------------------------------------------------------------
__device__ __forceinline__ void passA_body(
    unsigned char* smem,
    const int* __restrict__ src,
    const int* __restrict__ dst,
    const float* __restrict__ edge_feat,
    const float* __restrict__ We,
    const float* __restrict__ el,
    const float* __restrict__ er,
    int* __restrict__ ccursorH,
    uint3* __restrict__ wA,
    int half, int blk)
{
    int* ldst  = (int*)smem;              // 16384 B
    int* lbase = (int*)(smem + 16384);    //   100 B
    int* lcnt  = (int*)(smem + 16512);    //   100 B
    const int tid = threadIdx.x;
    if (tid < NBC) lcnt[tid] = 0;
    __syncthreads();
    const int hbeg = half ? E0 : 0;
    const int hend = half ? N_EDGES : E0;
    const int e0 = hbeg + blk * CHA;
    const int n = min(CHA, hend - e0);
    for (int i = tid; i < n; i += 1024) {
        const int d = dst[e0 + i];
        ldst[i] = d;
        atomicAdd(&lcnt[d >> 12], 1);
    }
    __syncthreads();
    if (tid < NBC) {
        const int c = lcnt[tid];
        lbase[tid] = c ? atomicAdd(&ccursorH[half * NBC + tid], c) : 0;
        lcnt[tid] = 0;
    }
    __syncthreads();

    const float4 W0 = ((const float4*)We)[0];
    const float4 W1 = ((const float4*)We)[1];
    const float4 W2 = ((const float4*)We)[2];
    const float4 W3 = ((const float4*)We)[3];

    for (int i = tid; i < n; i += 1024) {
        const int e = e0 + i;
        const int d = ldst[i];
        const int cb = d >> 12;
        const int r = atomicAdd(&lcnt[cb], 1);
        const int pos = lbase[cb] + r;

        const int s = src[e];
        const float4 ef = ((const float4*)edge_feat)[e];
        const float4 l4 = ((const float4*)el)[s];
        const float4 r4 = ((const float4*)er)[d];

        float t0 = l4.x + r4.x; t0 = t0 > 0.f ? t0 : 0.2f * t0;
        float t1 = l4.y + r4.y; t1 = t1 > 0.f ? t1 : 0.2f * t1;
        float t2 = l4.z + r4.z; t2 = t2 > 0.f ? t2 : 0.2f * t2;
        float t3 = l4.w + r4.w; t3 = t3 > 0.f ? t3 : 0.2f * t3;

        const float ee0 = __expf(t0 * (W0.x * ef.x + W0.y * ef.y + W0.z * ef.z + W0.w * ef.w));
        const float ee1 = __expf(t1 * (W1.x * ef.x + W1.y * ef.y + W1.z * ef.z + W1.w * ef.w));
        const float ee2 = __expf(t2 * (W2.x * ef.x + W2.y * ef.y + W2.z * ef.z + W2.w * ef.w));
        const float ee3 = __expf(t3 * (W3.x * ef.x + W3.y * ef.y + W3.z * ef.z + W3.w * ef.w));

        const unsigned h0 = __half_as_ushort(__float2half_rn(ee0));
        const unsigned h1 = __half_as_ushort(__float2half_rn(ee1));
        const unsigned h2 = __half_as_ushort(__float2half_rn(ee2));
        const unsigned h3 = __half_as_ushort(__float2half_rn(ee3));

        wA[pos] = make_uint3((unsigned)s | ((unsigned)(d & (CNODES - 1)) << 17),
                             h0 | (h1 << 16), h2 | (h3 << 16));
    }
}

// ---------------------------------------------------------------------------
// passB body: pure permutation coarse -> fine (782).
// ---------------------------------------------------------------------------
__device__ __forceinline__ void passB_body(
    unsigned char* smem,
    const int* __restrict__ cbaseH,
    int* __restrict__ fcursor,
    const uint3* __restrict__ wA,
    uint3* __restrict__ wB,
    int half, int blk)
{
    int* lcb   = (int*)smem;                        //   104 B
    int* lbase = (int*)(smem + 112);                //  3128 B
    int* lcnt  = (int*)(smem + 3240);               //  3128 B
    unsigned short* sfid = (unsigned short*)(smem + 6368);  //  8192 B
    uint3* sx  = (uint3*)(smem + 14576);            // 49152 B
    const int tid = threadIdx.x;
    for (int i = tid; i < NB; i += 1024) lcnt[i] = 0;
    if (tid < NBC + 1) lcb[tid] = cbaseH[half * (NBC + 1) + tid];
    __syncthreads();

    const int hsz = half ? E1REM : E0;
    const int p0 = blk * CHB;
    const int n = min(CHB, hsz - p0);
    for (int i = tid; i < n; i += 1024) {
        const uint3 x = wA[p0 + i];
        sx[i] = x;
        const int pos = p0 + i;
        int lo = 0, hi = NBC;
        while (lo + 1 < hi) {
            const int mid = (lo + hi) >> 1;
            if (lcb[mid] <= pos) lo = mid; else hi = mid;
        }
        const int dst12 = (int)((x.x >> 17) & (CNODES - 1));
        const int fid = lo * 32 + (dst12 >> 7);
        sfid[i] = (unsigned short)fid;
        atomicAdd(&lcnt[fid], 1);
    }
    __syncthreads();
    for (int b = tid; b < NB; b += 1024) {
        const int c = lcnt[b];
        lbase[b] = c ? atomicAdd(&fcursor[b], c) : 0;
        lcnt[b] = 0;
    }
    __syncthreads();
    for (int i = tid; i < n; i += 1024) {
        const uint3 x = sx[i];
        const int fid = sfid[i];
        const int r = atomicAdd(&lcnt[fid], 1);
        const unsigned dl = (x.x >> 17) & (BUCKET_NODES - 1);
        wB[lbase[fid] + r] = make_uint3((x.x & 0x1FFFFu) | (dl << 17), x.y, x.z);
    }
}

__global__ __launch_bounds__(1024) void passA(
    const int* __restrict__ src, const int* __restrict__ dst,
    const float* __restrict__ edge_feat, const float* __restrict__ We,
    const float* __restrict__ el, const float* __restrict__ er,
    int* __restrict__ ccursorH, uint3* __restrict__ wA, int half)
{
    __shared__ __align__(16) unsigned char smem[16640];
    passA_body(smem, src, dst, edge_feat, We, el, er, ccursorH, wA, half, blockIdx.x);
}

__global__ __launch_bounds__(1024) void passB(
    const int* __restrict__ cbaseH, int* __restrict__ fcursor,
    const uint3* __restrict__ wA, uint3* __restrict__ wB, int half)
{
    __shared__ __align__(16) unsigned char smem[63728];
    passB_body(smem, cbaseH, fcursor, wA, wB, half, blockIdx.x);
}

// ---------------------------------------------------------------------------
// sort_agg (R25-proven): fused finesort + aggregate, one block per bucket.
// ---------------------------------------------------------------------------
__global__ __launch_bounds__(1024) void sort_agg(
    const int* __restrict__ base,
    const uint3* __restrict__ wP,
    const unsigned short* __restrict__ featb,
    float* __restrict__ rst)
{
    __shared__ unsigned sA[FS_CAP];           // 18432 B  (then: (src*128))
    __shared__ unsigned sE[FS_CAP * 2];       // 36864 B  (ee01, ee23 fp16x2)
    __shared__ unsigned short inv[FS_CAP];    //  9216 B  sorted pos -> orig idx
    __shared__ int hist[BUCKET_NODES];        //    512 B
    __shared__ int off[BUCKET_NODES + 1];     //    516 B
    __shared__ int cur[BUCKET_NODES];         //    512 B
    const int b = blockIdx.x;
    const int s = base[b];
    int cnt = base[b + 1] - s;
    if (cnt > FS_CAP) cnt = FS_CAP;   // unreachable; safety
    const int tid = threadIdx.x;
    if (tid < BUCKET_NODES) hist[tid] = 0;
    __syncthreads();

    for (int i = tid; i < cnt; i += 1024) {
        const uint3 p = wP[s + i];
        sA[i] = p.x;
        sE[2 * i]     = p.y;
        sE[2 * i + 1] = p.z;
        atomicAdd(&hist[(p.x >> 17) & (BUCKET_NODES - 1)], 1);
    }
    __syncthreads();

    if (tid < 64) {
        int carry = 0;
        for (int ch = 0; ch < BUCKET_NODES; ch += 64) {
            const int v = hist[ch + tid];
            int x = v;
            #pragma unroll
            for (int o = 1; o < 64; o <<= 1) {
                int y = __shfl_up(x, o);
                if (tid >= o) x += y;
            }
            const int excl = x - v + carry;
            off[ch + tid] = excl;
            cur[ch + tid] = excl;
            carry += __shfl(x, 63);
        }
        if (tid == 0) off[BUCKET_NODES] = carry;   // == cnt
    }
    __syncthreads();

    for (int i = tid; i < cnt; i += 1024) {
        const unsigned a = sA[i];
        const int dl = (int)((a >> 17) & (BUCKET_NODES - 1));
        const int r = atomicAdd(&cur[dl], 1);
        inv[r] = (unsigned short)i;
        sA[i] = (a & 0x1FFFFu) << 7;        // pre-scale to featb byte offset
    }
    __syncthreads();

    // -------- aggregation from LDS --------
    const int lane = tid & 63;
    const int w = tid >> 6;
    const int half = lane >> 5;               // which edge of the pair
    const int j = lane & 31;                  // feature-pair index
    const int cc = j >> 3;                    // channel of features 2j,2j+1
    const unsigned jByte = (unsigned)j * 4u;
    const unsigned char* __restrict__ fbyte = (const unsigned char*)featb;
    const int node0 = b * BUCKET_NODES;

    #pragma unroll 1
    for (int nn = 0; nn < 8; ++nn) {
        const int nl = w * 8 + nn;
        const int node = node0 + nl;
        if (node >= N_NODES) break;
        const int st = off[nl];
        const int deg = off[nl + 1] - st;

        float acc0 = 0.f, acc1 = 0.f, scc = 0.f;
        const int iters = (deg + 1) >> 1;
        for (int i = 0; i < iters; ++i) {
            const int o = 2 * i + half;
            const bool valid = o < deg;
            const int pos = valid ? (st + o) : 0;   // bucket pos 0 valid when deg>0
            const int idx = (int)inv[pos];
            const unsigned so = sA[idx];
            const unsigned ed = sE[2 * idx + (cc >> 1)];
            float eec = __half2float(__ushort_as_half(
                (unsigned short)((cc & 1) ? (ed >> 16) : (ed & 0xffffu))));
            if (!valid) eec = 0.f;
            const unsigned fr = *(const unsigned*)(fbyte + so + jByte);
            acc0 = fmaf(eec, bf2f((unsigned short)(fr & 0xffffu)), acc0);
            acc1 = fmaf(eec, bf2f((unsigned short)(fr >> 16)), acc1);
            scc += eec;
        }

        const float a0 = acc0 + __shfl_xor(acc0, 32);
        const float a1 = acc1 + __shfl_xor(acc1, 32);
        const float ss = scc + __shfl_xor(scc, 32);

        const float v0 = __shfl(a0, lane >> 1);
        const float v1 = __shfl(a1, lane >> 1);
        const float sv = __shfl(ss, lane >> 1);
        const float accL = (lane & 1) ? v1 : v0;
        rst[(size_t)node * 64 + lane] = (deg > 0) ? accL / sv : 0.f;
    }
}

// ---------------------------------------------------------------------------
extern "C" void kernel_launch(void* const* d_in, const int* in_sizes, int n_in,
                              void* d_out, int out_size, void* d_ws, size_t ws_size,
                              hipStream_t stream)
{
    const float* node_feat = (const float*)d_in[0];
    const float* edge_feat = (const float*)d_in[1];
    const int*   src       = (const int*)d_in[2];
    const int*   dst       = (const int*)d_in[3];
    const float* Wfc       = (const float*)d_in[4];
    const float* We        = (const float*)d_in[5];
    const float* attn_l    = (const float*)d_in[6];
    const float* attn_r    = (const float*)d_in[7];
    float* rst = (float*)d_out;

    char* ws = (char*)d_ws;
    unsigned short* featb = (unsigned short*)(ws);        // 12,800,000 B
    float* el       = (float*)(ws + 12800000);            //  1,600,000 B
    float* er       = (float*)(ws + 14400000);            //  1,600,000 B
    int*   hhtot    = (int*)  (ws + 16000000);            //      6,256 B
    int*   base     = (int*)  (ws + 16006400);            //      3,132 B
    int*   fcursor  = (int*)  (ws + 16009600);            //      3,128 B
    int*   cbaseH   = (int*)  (ws + 16012800);            //        208 B
    int*   ccursorH = (int*)  (ws + 16013056);            //        200 B
    uint3* wB       = (uint3*)(ws + 16013312);            // 38,400,000 B
                                                          // total ~54.4 MB
    // d_out doubles as the per-half pass-A payload buffer (<=19.3 MB of 25.6);
    // halves are processed SEQUENTIALLY (A0,B0,A1,B1) because they share it.
    uint3* wA = (uint3*)d_out;

    hipMemsetAsync(hhtot, 0, 2 * NB * sizeof(int), stream);

    proj_hist<<<NPROJ + NHIST, 256, 0, stream>>>(
        node_feat, Wfc, attn_l, attn_r, featb, el, er, dst, hhtot);
    bscan<<<1, 64, 0, stream>>>(hhtot, base, fcursor, cbaseH, ccursorH);

    passA<<<NPA0, 1024, 0, stream>>>(src, dst, edge_feat, We, el, er, ccursorH, wA, 0);
    passB<<<NPB0, 1024, 0, stream>>>(cbaseH, fcursor, wA, wB, 0);
    passA<<<NPA1, 1024, 0, stream>>>(src, dst, edge_feat, We, el, er, ccursorH, wA, 1);
    passB<<<NPB1, 1024, 0, stream>>>(cbaseH, fcursor, wA, wB, 1);

    sort_agg<<<NB, 1024, 0, stream>>>(base, wB, featb, rst);
}